// Round 1
// baseline (531.958 us; speedup 1.0000x reference)
//
#include <hip/hip_runtime.h>
#include <stdint.h>

#define D 128
#define MT 64

typedef short short8 __attribute__((ext_vector_type(8)));
typedef float f32x16 __attribute__((ext_vector_type(16)));

__device__ __forceinline__ unsigned short f2bf(float f) {
    union { float f; uint32_t u; } v;
    v.f = f;
    uint32_t u = v.u;
    uint32_t r = (u + 0x7fffu + ((u >> 16) & 1u)) >> 16;  // RNE
    return (unsigned short)r;
}

// Pack W1 (384x128) / W2 (128x128) fp32 row-major -> bf16 MFMA-B fragment order:
// frag index ((kt*4 + nt)*64 + lane)*8 + j holds W[k = kt*16 + (lane>>5)*8 + j][n = nt*32 + (lane&31)]
__global__ void pack_weights_kernel(const float* __restrict__ W1,
                                    const float* __restrict__ W2,
                                    unsigned short* __restrict__ W1p,
                                    unsigned short* __restrict__ W2p) {
    int t = blockIdx.x * 256 + threadIdx.x;
    if (t < 6144) {               // W1: 24 ksteps * 4 colblocks * 64 lanes
        int kt = t >> 8, nt = (t >> 6) & 3, lane = t & 63;
        int n = nt * 32 + (lane & 31);
        int kb = kt * 16 + (lane >> 5) * 8;
        unsigned short* dst = W1p + t * 8;
        #pragma unroll
        for (int j = 0; j < 8; ++j) dst[j] = f2bf(W1[(kb + j) * D + n]);
    } else if (t < 8192) {        // W2: 8 ksteps * 4 colblocks * 64 lanes
        int u = t - 6144;
        int kt = u >> 8, nt = (u >> 6) & 3, lane = u & 63;
        int n = nt * 32 + (lane & 31);
        int kb = kt * 16 + (lane >> 5) * 8;
        unsigned short* dst = W2p + u * 8;
        #pragma unroll
        for (int j = 0; j < 8; ++j) dst[j] = f2bf(W2[(kb + j) * D + n]);
    }
}

// 64 edges per block, 256 threads = 4 waves. Wave w owns output columns [32w,32w+32),
// both 32-row tiles. X_cat staged bf16 in LDS (stride 392 = 49*16B -> uniform bank starts).
// H aliases the same LDS (barrier-separated) to stay <= 50 KB -> 3 blocks/CU.
__global__ __launch_bounds__(256, 3) void edge_mlp_kernel(
    const float* __restrict__ x_node,
    const float* __restrict__ x_edge,
    const int* __restrict__ eidx,
    const unsigned short* __restrict__ W1p,
    const unsigned short* __restrict__ W2p,
    const float* __restrict__ b1,
    const float* __restrict__ b2,
    float* __restrict__ out,
    int E) {
    __shared__ unsigned short lds[MT * 392];   // 50176 B
    unsigned short* Hs = lds;                  // aliased, stride 136 (17*16B)

    const int t = threadIdx.x;
    const int r0 = blockIdx.x * MT;

    // ---- stage: gather v0|v1|x_edge, convert fp32->bf16, write LDS ----
    {
        const int lane32 = t & 31;
        const int rsub = t >> 5;               // 0..7
        #pragma unroll
        for (int rb = 0; rb < 8; ++rb) {
            int row = rb * 8 + rsub;           // 0..63
            int rg = r0 + row;
            int rgc = rg < E ? rg : E - 1;
            int e0 = eidx[2 * rgc];
            int e1 = eidx[2 * rgc + 1];
            float4 v0 = ((const float4*)(x_node + (size_t)e0 * D))[lane32];
            float4 v1 = ((const float4*)(x_node + (size_t)e1 * D))[lane32];
            float4 v2 = ((const float4*)(x_edge + (size_t)rgc * D))[lane32];
            unsigned short* base = &lds[row * 392 + lane32 * 4];
            ushort4 p;
            p.x = f2bf(v0.x); p.y = f2bf(v0.y); p.z = f2bf(v0.z); p.w = f2bf(v0.w);
            *(ushort4*)(base) = p;
            p.x = f2bf(v1.x); p.y = f2bf(v1.y); p.z = f2bf(v1.z); p.w = f2bf(v1.w);
            *(ushort4*)(base + 128) = p;
            p.x = f2bf(v2.x); p.y = f2bf(v2.y); p.z = f2bf(v2.z); p.w = f2bf(v2.w);
            *(ushort4*)(base + 256) = p;
        }
    }
    __syncthreads();

    const int w = t >> 6;                 // wave id -> column block
    const int lane = t & 63;
    const int lrow = lane & 31;           // m within 32-tile / n within col block
    const int khalf = (lane >> 5) * 8;    // k-half select
    const int n = w * 32 + lrow;
    const int rbump = (lane >> 5) * 4;

    // ---- GEMM1: H = relu(X_cat @ W1 + b1), K = 384 ----
    f32x16 acc0, acc1;
    #pragma unroll
    for (int i = 0; i < 16; ++i) { acc0[i] = 0.f; acc1[i] = 0.f; }

    for (int kt = 0; kt < 24; ++kt) {
        short8 a0 = *(const short8*)&lds[lrow * 392 + kt * 16 + khalf];
        short8 a1 = *(const short8*)&lds[(lrow + 32) * 392 + kt * 16 + khalf];
        short8 b  = *(const short8*)(W1p + ((kt * 4 + w) * 64 + lane) * 8);
        acc0 = __builtin_amdgcn_mfma_f32_32x32x16_bf16(a0, b, acc0, 0, 0, 0);
        acc1 = __builtin_amdgcn_mfma_f32_32x32x16_bf16(a1, b, acc1, 0, 0, 0);
    }
    __syncthreads();   // everyone done reading X_cat before H overwrites it

    {
        float b1v = b1[n];
        #pragma unroll
        for (int r = 0; r < 16; ++r) {
            int rr = (r & 3) + 8 * (r >> 2) + rbump;   // C-layout row within tile
            float h0 = fmaxf(acc0[r] + b1v, 0.f);
            float h1 = fmaxf(acc1[r] + b1v, 0.f);
            Hs[rr * 136 + n] = f2bf(h0);
            Hs[(rr + 32) * 136 + n] = f2bf(h1);
        }
    }
    __syncthreads();

    // ---- GEMM2: OUT = H @ W2 + b2, K = 128 ----
    f32x16 c0, c1;
    #pragma unroll
    for (int i = 0; i < 16; ++i) { c0[i] = 0.f; c1[i] = 0.f; }

    #pragma unroll
    for (int kt = 0; kt < 8; ++kt) {
        short8 a0 = *(const short8*)&Hs[lrow * 136 + kt * 16 + khalf];
        short8 a1 = *(const short8*)&Hs[(lrow + 32) * 136 + kt * 16 + khalf];
        short8 b  = *(const short8*)(W2p + ((kt * 4 + w) * 64 + lane) * 8);
        c0 = __builtin_amdgcn_mfma_f32_32x32x16_bf16(a0, b, c0, 0, 0, 0);
        c1 = __builtin_amdgcn_mfma_f32_32x32x16_bf16(a1, b, c1, 0, 0, 0);
    }

    {
        float b2v = b2[n];
        #pragma unroll
        for (int r = 0; r < 16; ++r) {
            int rr = (r & 3) + 8 * (r >> 2) + rbump;
            int rg = r0 + rr;
            if (rg < E) out[(size_t)rg * D + n] = c0[r] + b2v;
            if (rg + 32 < E) out[(size_t)(rg + 32) * D + n] = c1[r] + b2v;
        }
    }
}

extern "C" void kernel_launch(void* const* d_in, const int* in_sizes, int n_in,
                              void* d_out, int out_size, void* d_ws, size_t ws_size,
                              hipStream_t stream) {
    const float* x_node = (const float*)d_in[0];
    const float* x_edge = (const float*)d_in[1];
    const int*   eidx   = (const int*)d_in[2];
    const float* W1     = (const float*)d_in[3];
    const float* b1     = (const float*)d_in[4];
    const float* W2     = (const float*)d_in[5];
    const float* b2     = (const float*)d_in[6];
    float* out = (float*)d_out;

    const int E = in_sizes[1] / D;

    unsigned short* W1p = (unsigned short*)d_ws;          // 6144*8 bf16 = 96 KB
    unsigned short* W2p = W1p + 6144 * 8;                 // 2048*8 bf16 = 32 KB

    pack_weights_kernel<<<32, 256, 0, stream>>>(W1, W2, W1p, W2p);

    int nblk = (E + MT - 1) / MT;
    edge_mlp_kernel<<<nblk, 256, 0, stream>>>(x_node, x_edge, eidx, W1p, W2p, b1, b2, out, E);
}